// Round 6
// baseline (254.242 us; speedup 1.0000x reference)
//
#include <hip/hip_runtime.h>
#include <math.h>

// Problem constants
#define NS    8000      // N samples
#define TT    64        // T
#define FF    64        // F
#define EE    8         // E
#define WIN   40        // WINDOW
#define TR    59        // rows of xe kept: t = 5..63
#define NBINS 4096

// ws layout (floats):
//   xeT  [8][59][8000]  = 3,776,000
//   rankT[8][40][8000]  = 2,560,000
//   uraw [8000][40][5]  = 1,600,000
#define XET_SZ  (8*59*8000)
#define RNK_SZ  (8*40*8000)

// ---------------------------------------------------------------------------
// K0: fused transpose + raw-channel conv fold.
// Thread (n, r): r = t-5 in 0..58. Always: transpose x[:, 5+r, 0:8] -> xeT.
// For r>=19 (t=24..63, w=r-19): load full 64-feature row, fold into
// u[n][w][k] = dot(row, W127[:,k]). W offsets are lane-uniform -> scalar
// loads; no LDS, no shuffles.
// ---------------------------------------------------------------------------
__global__ __launch_bounds__(256) void k0(const float* __restrict__ x,
                                          const float* __restrict__ cw,
                                          float* __restrict__ xeT,
                                          float* __restrict__ uraw) {
    int n = blockIdx.x * 256 + threadIdx.x;
    int r = blockIdx.y;              // 0..58
    if (n >= NS) return;
    const float* row = x + (size_t)n * (TT * FF) + (5 + r) * FF;
    float4 a = *(const float4*)(row);
    float4 b = *(const float4*)(row + 4);
    xeT[(0 * TR + r) * NS + n] = a.x;
    xeT[(1 * TR + r) * NS + n] = a.y;
    xeT[(2 * TR + r) * NS + n] = a.z;
    xeT[(3 * TR + r) * NS + n] = a.w;
    xeT[(4 * TR + r) * NS + n] = b.x;
    xeT[(5 * TR + r) * NS + n] = b.y;
    xeT[(6 * TR + r) * NS + n] = b.z;
    xeT[(7 * TR + r) * NS + n] = b.w;

    if (r >= 19) {                   // t = 24+w, w = r-19
        const int w = r - 19;
        const float* W = cw + 127 * 144 * 5;
        float4 v[16];
        v[0] = a; v[1] = b;
#pragma unroll
        for (int q = 2; q < 16; q++) v[q] = *(const float4*)(row + 4 * q);
        float acc0 = 0.f, acc1 = 0.f, acc2 = 0.f, acc3 = 0.f, acc4 = 0.f;
#pragma unroll
        for (int q = 0; q < 16; q++) {
            const float* Wq = W + (4 * q) * 5;   // uniform -> s_load
            acc0 += v[q].x * Wq[0]  + v[q].y * Wq[5]  + v[q].z * Wq[10] + v[q].w * Wq[15];
            acc1 += v[q].x * Wq[1]  + v[q].y * Wq[6]  + v[q].z * Wq[11] + v[q].w * Wq[16];
            acc2 += v[q].x * Wq[2]  + v[q].y * Wq[7]  + v[q].z * Wq[12] + v[q].w * Wq[17];
            acc3 += v[q].x * Wq[3]  + v[q].y * Wq[8]  + v[q].z * Wq[13] + v[q].w * Wq[18];
            acc4 += v[q].x * Wq[4]  + v[q].y * Wq[9]  + v[q].z * Wq[14] + v[q].w * Wq[19];
        }
        float* o = uraw + ((size_t)n * WIN + w) * 5;
        o[0] = acc0; o[1] = acc1; o[2] = acc2; o[3] = acc3; o[4] = acc4;
    }
}

// ---------------------------------------------------------------------------
// KR v4: exact cross-batch descending rank (stable ties by index).
// 512 threads/block, 4096 bins over [-4,4] (avg same-bucket ~4.4).
// LDS 72.6 KB (hist u32 + basev u16 + sk f32 + si u16) -> 2 blocks/CU by
// LDS; __launch_bounds__(512,4) caps VGPR<=128 so 16 waves/CU -> ALL 320
// blocks resident in one round. Output staged via LDS for coalesced store.
// ---------------------------------------------------------------------------
__device__ __forceinline__ int binOf(float v) {
    int b = (int)((v + 4.0f) * 512.0f);   // monotone; clamped
    b = b < 0 ? 0 : b;
    return b > (NBINS - 1) ? (NBINS - 1) : b;
}

__global__ __launch_bounds__(512, 4) void k_rank(const float* __restrict__ xeT,
                                                 float* __restrict__ rankT) {
    const int w = blockIdx.x;   // 0..39
    const int e = blockIdx.y;   // 0..7
    __shared__ unsigned hist[NBINS];              // 16 KB (scatter cursor)
    __shared__ unsigned short basev[NBINS];       // 8 KB, values <= 8000
    __shared__ float          sk[NS];             // 32 KB, bucket-grouped vals
    __shared__ unsigned short si[NS];             // 16 KB, orig idx / ranks
    __shared__ unsigned wsum[8];

    const int tid  = threadIdx.x;
    const int lane = tid & 63;
    const int wid  = tid >> 6;                    // 0..7
    const float* col = xeT + ((size_t)e * TR + (19 + w)) * NS;   // t = 24+w

    float val[16];
#pragma unroll
    for (int i = 0; i < 16; i++) {
        int idx = tid + i * 512;
        val[i] = (idx < NS) ? col[idx] : 0.0f;
    }
#pragma unroll
    for (int j = 0; j < 8; j++) hist[tid + j * 512] = 0;
    __syncthreads();

#pragma unroll
    for (int i = 0; i < 16; i++) {
        int idx = tid + i * 512;
        if (idx < NS) atomicAdd(&hist[binOf(val[i])], 1u);
    }
    __syncthreads();

    // suffix offsets: 8 bins/thread; wave scan + cross-wave offsets
    unsigned h[8];
#pragma unroll
    for (int j = 0; j < 8; j++) h[j] = hist[8 * tid + j];
    unsigned cs = 0;
#pragma unroll
    for (int j = 0; j < 8; j++) cs += h[j];
    unsigned sc = cs;
#pragma unroll
    for (int d = 1; d < 64; d <<= 1) {
        unsigned t2 = __shfl_up(sc, d);
        if (lane >= d) sc += t2;
    }
    if (lane == 63) wsum[wid] = sc;
    __syncthreads();
    unsigned woff = 0;
    for (int i = 0; i < wid; i++) woff += wsum[i];
    unsigned bsum = woff + (sc - cs);   // # elements in bins < 8*tid
#pragma unroll
    for (int j = 0; j < 8; j++) {
        int b = 8 * tid + j;
        unsigned bv = NS - bsum - h[j];          // # elems in bins > b
        basev[b] = (unsigned short)bv;
        hist[b]  = bv;                           // scatter cursor
        bsum += h[j];
    }
    __syncthreads();

    // scatter into bucket-grouped order (order within bucket irrelevant)
#pragma unroll
    for (int i = 0; i < 16; i++) {
        int idx = tid + i * 512;
        if (idx < NS) {
            int b = binOf(val[i]);
            unsigned p = atomicAdd(&hist[b], 1u);
            sk[p] = val[i];
            si[p] = (unsigned short)idx;
        }
    }
    __syncthreads();

    // exact rank: greater-bucket count + within-bucket (value desc, idx asc).
    // Consecutive p -> lanes in adjacent buckets -> broadcast-ish reads.
    // packed[i] = (idm << 16) | rank
    unsigned packed[16];
#pragma unroll 1
    for (int i = 0; i < 16; i++) {
        int p = tid + i * 512;
        packed[i] = 0xFFFFFFFFu;
        if (p < NS) {
            float v = sk[p];
            unsigned idm = si[p];
            int b = binOf(v);
            unsigned lo = basev[b];
            unsigned hi = (b == 0) ? NS : (unsigned)basev[b - 1];
            unsigned c = 0;
            for (unsigned q = lo; q < hi; q++) {
                float u2 = sk[q];
                if (u2 > v) c++;
                else if (u2 == v) {            // ties ~never: wave skips
                    if (si[q] < idm) c++;
                }
            }
            packed[i] = (idm << 16) | ((unsigned)basev[b] + c);
        }
    }
    __syncthreads();   // all tie-path reads of si[] done

    // stage ranks into si[idm], then coalesced global store
#pragma unroll
    for (int i = 0; i < 16; i++) {
        if (packed[i] != 0xFFFFFFFFu)
            si[packed[i] >> 16] = (unsigned short)(packed[i] & 0xFFFFu);
    }
    __syncthreads();

    float* outp = rankT + ((size_t)e * WIN + w) * NS;
#pragma unroll
    for (int i = 0; i < 16; i++) {
        int t = tid + i * 512;
        if (t < NS) outp[t] = (float)si[t] * (1.0f / 8000.0f);
    }
}

// ---------------------------------------------------------------------------
// KDF: fused derived-stats + conv-fold + epilogue. Thread = (n,e); 20-reg
// sliding ring over 59 xeT rows (xeT read exactly once). Weights preloaded
// to registers. LDS e-reduction ([8][32][37], conflict-free); 32 threads do
// the leaky+dot epilogue per block.
// ---------------------------------------------------------------------------
__global__ __launch_bounds__(256) void k_der_final(const float* __restrict__ cw,
                                                   const float* __restrict__ xeT,
                                                   const float* __restrict__ rankT,
                                                   const float* __restrict__ uraw,
                                                   const float* __restrict__ cb,
                                                   const float* __restrict__ lw,
                                                   const float* __restrict__ lb,
                                                   float* __restrict__ outp) {
    __shared__ float red[8][32][37];
    const int tid = threadIdx.x;
    const int e   = tid >> 5;          // 0..7
    const int nl  = tid & 31;          // 0..31
    const int n0  = blockIdx.x * 32;   // 250 blocks * 32 = 8000
    const int n   = n0 + nl;
    const float* W = cw + 127 * 144 * 5;

    // preload this e's 45 weights (rank folds two channels)
    float wm5[5], wsd5[5], wrk[5], wmx5[5], wmn5[5], wm20[5], wsd20[5], wmx20[5], wmn20[5];
#pragma unroll
    for (int k = 0; k < 5; k++) {
        wm5[k]   = W[(64  + e) * 5 + k];
        wsd5[k]  = W[(72  + e) * 5 + k];
        wrk[k]   = W[(80  + e) * 5 + k] + W[(120 + e) * 5 + k];
        wmx5[k]  = W[(88  + e) * 5 + k];
        wmn5[k]  = W[(96  + e) * 5 + k];
        wm20[k]  = W[(104 + e) * 5 + k];
        wsd20[k] = W[(112 + e) * 5 + k];
        wmx20[k] = W[(128 + e) * 5 + k];
        wmn20[k] = W[(136 + e) * 5 + k];
    }

    float gder[36];
#pragma unroll
    for (int j = 0; j < 36; j++) gder[j] = 0.0f;

    const float* col = xeT + (size_t)e * TR * NS + n;
    const float* rkp = rankT + (size_t)e * WIN * NS + n;

    float ring[20];
#pragma unroll
    for (int r = 0; r < 19; r++) ring[r] = col[(size_t)r * NS];

#pragma unroll
    for (int w = 0; w < WIN; w++) {
        ring[(w + 19) % 20] = col[(size_t)(w + 19) * NS];
        // month window = rows w..w+19 (all 20 ring slots; order irrelevant)
        float s20 = 0.f, mn20 = ring[0], mx20 = ring[0];
#pragma unroll
        for (int i = 0; i < 20; i++) {
            float v = ring[i];
            s20 += v; mn20 = fminf(mn20, v); mx20 = fmaxf(mx20, v);
        }
        float m20 = s20 * (1.0f / 20.0f);
        float d20 = 0.f;
#pragma unroll
        for (int i = 0; i < 20; i++) { float t = ring[i] - m20; d20 += t * t; }
        float sd20 = sqrtf(d20 * (1.0f / 19.0f));

        // week window = rows w+15..w+19
        float s5 = 0.f, mn5 = ring[(w + 15) % 20], mx5 = mn5;
#pragma unroll
        for (int i = 15; i < 20; i++) {
            float v = ring[(w + i) % 20];
            s5 += v; mn5 = fminf(mn5, v); mx5 = fmaxf(mx5, v);
        }
        float m5 = s5 * 0.2f;
        float d5 = 0.f;
#pragma unroll
        for (int i = 15; i < 20; i++) {
            float t = ring[(w + i) % 20] - m5; d5 += t * t;
        }
        float sd5 = sqrtf(d5 * 0.25f);

        float rk = rkp[(size_t)w * NS];

#pragma unroll
        for (int k = 0; k < 5; k++) {
            int j = w - k;
            if (j >= 0 && j < 36) {
                float uk;
                uk  = m5   * wm5[k];
                uk += sd5  * wsd5[k];
                uk += rk   * wrk[k];
                uk += mx5  * wmx5[k];
                uk += mn5  * wmn5[k];
                uk += m20  * wm20[k];
                uk += sd20 * wsd20[k];
                uk += mx20 * wmx20[k];
                uk += mn20 * wmn20[k];
                gder[j] += uk;
            }
        }
    }

    // stage partials: red[e][nl][j]; consecutive tid -> addr stride 37 (cf-free)
#pragma unroll
    for (int j = 0; j < 36; j++) red[e][nl][j] = gder[j];
    __syncthreads();

    // reduce over e: thread owns (nl2,j) pairs; writes into red[0][nl2][j]
    for (int p = tid; p < 32 * 36; p += 256) {
        int nl2 = p / 36, j = p - nl2 * 36;
        float sum = 0.f;
#pragma unroll
        for (int e2 = 0; e2 < 8; e2++) sum += red[e2][nl2][j];
        red[0][nl2][j] = sum;     // only this thread reads/writes (nl2,j)
    }
    __syncthreads();

    // epilogue: 32 threads, one n each
    if (tid < 32) {
        const float* ur = uraw + (size_t)n * (WIN * 5);
        float b127 = cb[127];
        float acc = lb[0];
#pragma unroll
        for (int j = 0; j < 36; j++) {
            float g = b127 + red[0][tid][j];
#pragma unroll
            for (int k = 0; k < 5; k++) g += ur[(j + k) * 5 + k];
            g = (g >= 0.0f) ? g : 0.01f * g;
            acc += g * lw[j];
        }
        outp[n] = acc;
    }
}

// ---------------------------------------------------------------------------
extern "C" void kernel_launch(void* const* d_in, const int* in_sizes, int n_in,
                              void* d_out, int out_size, void* d_ws, size_t ws_size,
                              hipStream_t stream) {
    const float* x  = (const float*)d_in[0];   // [8000,64,64]
    const float* cw = (const float*)d_in[1];   // [128,144,5]
    const float* cb = (const float*)d_in[2];   // [128]
    const float* lw = (const float*)d_in[3];   // [1,36]
    const float* lb = (const float*)d_in[4];   // [1]
    float* outp = (float*)d_out;               // [8000,1]

    float* ws    = (float*)d_ws;
    float* xeT   = ws;                         // 8*59*8000
    float* rankT = ws + XET_SZ;                // 8*40*8000
    float* uraw  = ws + XET_SZ + RNK_SZ;       // 8000*40*5

    k0<<<dim3(32, 59), 256, 0, stream>>>(x, cw, xeT, uraw);
    k_rank<<<dim3(WIN, EE), 512, 0, stream>>>(xeT, rankT);
    k_der_final<<<250, 256, 0, stream>>>(cw, xeT, rankT, uraw, cb, lw, lb, outp);
}

// Round 7
// 246.444 us; speedup vs baseline: 1.0316x; 1.0316x over previous
//
#include <hip/hip_runtime.h>
#include <math.h>

// Problem constants
#define NS    8000      // N samples
#define TT    64        // T
#define FF    64        // F
#define EE    8         // E
#define WIN   40        // WINDOW
#define TR    59        // rows of xe kept: t = 5..63
#define NBINS 16384

// ws layout (floats):
//   xeT  [8][59][8000]  = 3,776,000
//   rankT[8][40][8000]  = 2,560,000
//   uraw [8000][40][5]  = 1,600,000
#define XET_SZ  (8*59*8000)
#define RNK_SZ  (8*40*8000)

// ---------------------------------------------------------------------------
// K0: fused transpose + raw-channel conv fold.
// Thread (n, r): r = t-5 in 0..58. Always: transpose x[:, 5+r, 0:8] -> xeT.
// For r>=19 (t=24..63, w=r-19): load full 64-feature row, fold into
// u[n][w][k] = dot(row, W127[:,k]). W offsets are lane-uniform -> scalar
// loads; no LDS, no shuffles.
// ---------------------------------------------------------------------------
__global__ __launch_bounds__(256) void k0(const float* __restrict__ x,
                                          const float* __restrict__ cw,
                                          float* __restrict__ xeT,
                                          float* __restrict__ uraw) {
    int n = blockIdx.x * 256 + threadIdx.x;
    int r = blockIdx.y;              // 0..58
    if (n >= NS) return;
    const float* row = x + (size_t)n * (TT * FF) + (5 + r) * FF;
    float4 a = *(const float4*)(row);
    float4 b = *(const float4*)(row + 4);
    xeT[(0 * TR + r) * NS + n] = a.x;
    xeT[(1 * TR + r) * NS + n] = a.y;
    xeT[(2 * TR + r) * NS + n] = a.z;
    xeT[(3 * TR + r) * NS + n] = a.w;
    xeT[(4 * TR + r) * NS + n] = b.x;
    xeT[(5 * TR + r) * NS + n] = b.y;
    xeT[(6 * TR + r) * NS + n] = b.z;
    xeT[(7 * TR + r) * NS + n] = b.w;

    if (r >= 19) {                   // t = 24+w, w = r-19
        const int w = r - 19;
        const float* W = cw + 127 * 144 * 5;
        float4 v[16];
        v[0] = a; v[1] = b;
#pragma unroll
        for (int q = 2; q < 16; q++) v[q] = *(const float4*)(row + 4 * q);
        float acc0 = 0.f, acc1 = 0.f, acc2 = 0.f, acc3 = 0.f, acc4 = 0.f;
#pragma unroll
        for (int q = 0; q < 16; q++) {
            const float* Wq = W + (4 * q) * 5;   // uniform -> s_load
            acc0 += v[q].x * Wq[0]  + v[q].y * Wq[5]  + v[q].z * Wq[10] + v[q].w * Wq[15];
            acc1 += v[q].x * Wq[1]  + v[q].y * Wq[6]  + v[q].z * Wq[11] + v[q].w * Wq[16];
            acc2 += v[q].x * Wq[2]  + v[q].y * Wq[7]  + v[q].z * Wq[12] + v[q].w * Wq[17];
            acc3 += v[q].x * Wq[3]  + v[q].y * Wq[8]  + v[q].z * Wq[13] + v[q].w * Wq[18];
            acc4 += v[q].x * Wq[4]  + v[q].y * Wq[9]  + v[q].z * Wq[14] + v[q].w * Wq[19];
        }
        float* o = uraw + ((size_t)n * WIN + w) * 5;
        o[0] = acc0; o[1] = acc1; o[2] = acc2; o[3] = acc3; o[4] = acc4;
    }
}

// ---------------------------------------------------------------------------
// KR v5: exact cross-batch descending rank via 64-bit sortable keys.
// key = (mono_desc(v) << 13) | idx  -> rank = #{key_j < key_i}, which exactly
// matches stable argsort(-v) (value desc, index asc). 16384 value-linear
// bins over [-4,4]: element-weighted avg bucket ~2.1 -> ~2 branchless
// ds_read_b64 compares per element. basev[] eliminated: after the scatter,
// hist[b] == bend[b], and basev[b] == hist[b+1]. LDS = 64K hist + 64K keys
// = 126.6 KB -> 1 block/CU, 16 waves (v3-equivalent residency).
// Output ranks staged through hist-memory (u16) for a coalesced store.
// ---------------------------------------------------------------------------
__device__ __forceinline__ int binOf(float v) {
    int b = (int)((v + 4.0f) * 2048.0f);   // monotone; clamped
    b = b < 0 ? 0 : b;
    return b > (NBINS - 1) ? (NBINS - 1) : b;
}

__device__ __forceinline__ unsigned long long keyOf(float v, unsigned idx) {
    unsigned s = __float_as_uint(v);
    unsigned m = (s & 0x80000000u) ? (~s) : (s | 0x80000000u); // ascending mono
    unsigned md = ~m;                                          // descending
    return ((unsigned long long)md << 13) | idx;               // idx < 8192
}

__global__ __launch_bounds__(1024) void k_rank(const float* __restrict__ xeT,
                                               float* __restrict__ rankT) {
    const int w = blockIdx.x;   // 0..39
    const int e = blockIdx.y;   // 0..7
    __shared__ unsigned hist[NBINS];             // 64 KB: cursor -> bend -> rank stage
    __shared__ unsigned long long sk[NS];        // 64 KB: bucket-grouped keys
    __shared__ unsigned wsum[16];

    const int tid  = threadIdx.x;
    const int lane = tid & 63;
    const int wid  = tid >> 6;
    const float* col = xeT + ((size_t)e * TR + (19 + w)) * NS;   // t = 24+w

    float val[8];
#pragma unroll
    for (int i = 0; i < 8; i++) {
        int idx = tid + i * 1024;
        val[i] = (idx < NS) ? col[idx] : 0.0f;
    }
#pragma unroll
    for (int j = 0; j < 16; j++) hist[tid + j * 1024] = 0;
    __syncthreads();

#pragma unroll
    for (int i = 0; i < 8; i++) {
        int idx = tid + i * 1024;
        if (idx < NS) atomicAdd(&hist[binOf(val[i])], 1u);
    }
    __syncthreads();

    // suffix offsets: 16 bins/thread; wave scan + cross-wave offsets
    unsigned h[16];
#pragma unroll
    for (int j = 0; j < 16; j++) h[j] = hist[16 * tid + j];
    unsigned cs = 0;
#pragma unroll
    for (int j = 0; j < 16; j++) cs += h[j];
    unsigned sc = cs;
#pragma unroll
    for (int d = 1; d < 64; d <<= 1) {
        unsigned t2 = __shfl_up(sc, d);
        if (lane >= d) sc += t2;
    }
    if (lane == 63) wsum[wid] = sc;
    __syncthreads();
    unsigned woff = 0;
    for (int i = 0; i < wid; i++) woff += wsum[i];
    unsigned bsum = woff + (sc - cs);   // # elements in bins < 16*tid
#pragma unroll
    for (int j = 0; j < 16; j++) {
        int b = 16 * tid + j;
        hist[b] = NS - bsum - h[j];     // basev[b] = scatter cursor
        bsum += h[j];
    }
    __syncthreads();

    // scatter keys into bucket-grouped order (order within bucket irrelevant)
#pragma unroll
    for (int i = 0; i < 8; i++) {
        int idx = tid + i * 1024;
        if (idx < NS) {
            int b = binOf(val[i]);
            unsigned p = atomicAdd(&hist[b], 1u);
            sk[p] = keyOf(val[i], (unsigned)idx);
        }
    }
    __syncthreads();
    // now hist[b] == bend[b]; basev[b] == (b==NBINS-1 ? 0 : hist[b+1])

    // exact rank: branchless within-bucket u64 compares
    unsigned packed[8];                  // (idm << 16) | rank
#pragma unroll 1
    for (int i = 0; i < 8; i++) {
        int p = tid + i * 1024;
        packed[i] = 0xFFFFFFFFu;
        if (p < NS) {
            unsigned long long k64 = sk[p];
            unsigned md = (unsigned)(k64 >> 13);
            unsigned m  = ~md;
            unsigned s  = (m & 0x80000000u) ? (m ^ 0x80000000u) : (~m);
            float v = __uint_as_float(s);
            int b = binOf(v);
            unsigned lo = (b == NBINS - 1) ? 0u : hist[b + 1];
            unsigned hi = hist[b];
            unsigned c = 0;
            for (unsigned q = lo; q < hi; q++) c += (sk[q] < k64);
            packed[i] = (((unsigned)(k64 & 8191u)) << 16) | (lo + c);
        }
    }
    __syncthreads();   // all scans done; hist memory now free

    // stage ranks (u16) into hist memory, then coalesced global store
    unsigned short* stg = (unsigned short*)hist;
#pragma unroll
    for (int i = 0; i < 8; i++) {
        if (packed[i] != 0xFFFFFFFFu)
            stg[packed[i] >> 16] = (unsigned short)(packed[i] & 0xFFFFu);
    }
    __syncthreads();

    float* outp = rankT + ((size_t)e * WIN + w) * NS;
#pragma unroll
    for (int i = 0; i < 8; i++) {
        int t = tid + i * 1024;
        if (t < NS) outp[t] = (float)stg[t] * (1.0f / 8000.0f);
    }
}

// ---------------------------------------------------------------------------
// KDF: fused derived-stats + conv-fold + epilogue. Thread = (n,e); 20-reg
// sliding ring over 59 xeT rows (xeT read exactly once). Weights preloaded
// to registers. LDS e-reduction ([8][32][37], conflict-free); 32 threads do
// the leaky+dot epilogue per block.
// ---------------------------------------------------------------------------
__global__ __launch_bounds__(256) void k_der_final(const float* __restrict__ cw,
                                                   const float* __restrict__ xeT,
                                                   const float* __restrict__ rankT,
                                                   const float* __restrict__ uraw,
                                                   const float* __restrict__ cb,
                                                   const float* __restrict__ lw,
                                                   const float* __restrict__ lb,
                                                   float* __restrict__ outp) {
    __shared__ float red[8][32][37];
    const int tid = threadIdx.x;
    const int e   = tid >> 5;          // 0..7
    const int nl  = tid & 31;          // 0..31
    const int n0  = blockIdx.x * 32;   // 250 blocks * 32 = 8000
    const int n   = n0 + nl;
    const float* W = cw + 127 * 144 * 5;

    // preload this e's 45 weights (rank folds two channels)
    float wm5[5], wsd5[5], wrk[5], wmx5[5], wmn5[5], wm20[5], wsd20[5], wmx20[5], wmn20[5];
#pragma unroll
    for (int k = 0; k < 5; k++) {
        wm5[k]   = W[(64  + e) * 5 + k];
        wsd5[k]  = W[(72  + e) * 5 + k];
        wrk[k]   = W[(80  + e) * 5 + k] + W[(120 + e) * 5 + k];
        wmx5[k]  = W[(88  + e) * 5 + k];
        wmn5[k]  = W[(96  + e) * 5 + k];
        wm20[k]  = W[(104 + e) * 5 + k];
        wsd20[k] = W[(112 + e) * 5 + k];
        wmx20[k] = W[(128 + e) * 5 + k];
        wmn20[k] = W[(136 + e) * 5 + k];
    }

    float gder[36];
#pragma unroll
    for (int j = 0; j < 36; j++) gder[j] = 0.0f;

    const float* col = xeT + (size_t)e * TR * NS + n;
    const float* rkp = rankT + (size_t)e * WIN * NS + n;

    float ring[20];
#pragma unroll
    for (int r = 0; r < 19; r++) ring[r] = col[(size_t)r * NS];

#pragma unroll
    for (int w = 0; w < WIN; w++) {
        ring[(w + 19) % 20] = col[(size_t)(w + 19) * NS];
        // month window = rows w..w+19 (all 20 ring slots; order irrelevant)
        float s20 = 0.f, mn20 = ring[0], mx20 = ring[0];
#pragma unroll
        for (int i = 0; i < 20; i++) {
            float v = ring[i];
            s20 += v; mn20 = fminf(mn20, v); mx20 = fmaxf(mx20, v);
        }
        float m20 = s20 * (1.0f / 20.0f);
        float d20 = 0.f;
#pragma unroll
        for (int i = 0; i < 20; i++) { float t = ring[i] - m20; d20 += t * t; }
        float sd20 = sqrtf(d20 * (1.0f / 19.0f));

        // week window = rows w+15..w+19
        float s5 = 0.f, mn5 = ring[(w + 15) % 20], mx5 = mn5;
#pragma unroll
        for (int i = 15; i < 20; i++) {
            float v = ring[(w + i) % 20];
            s5 += v; mn5 = fminf(mn5, v); mx5 = fmaxf(mx5, v);
        }
        float m5 = s5 * 0.2f;
        float d5 = 0.f;
#pragma unroll
        for (int i = 15; i < 20; i++) {
            float t = ring[(w + i) % 20] - m5; d5 += t * t;
        }
        float sd5 = sqrtf(d5 * 0.25f);

        float rk = rkp[(size_t)w * NS];

#pragma unroll
        for (int k = 0; k < 5; k++) {
            int j = w - k;
            if (j >= 0 && j < 36) {
                float uk;
                uk  = m5   * wm5[k];
                uk += sd5  * wsd5[k];
                uk += rk   * wrk[k];
                uk += mx5  * wmx5[k];
                uk += mn5  * wmn5[k];
                uk += m20  * wm20[k];
                uk += sd20 * wsd20[k];
                uk += mx20 * wmx20[k];
                uk += mn20 * wmn20[k];
                gder[j] += uk;
            }
        }
    }

    // stage partials: red[e][nl][j]; consecutive tid -> addr stride 37 (cf-free)
#pragma unroll
    for (int j = 0; j < 36; j++) red[e][nl][j] = gder[j];
    __syncthreads();

    // reduce over e: thread owns (nl2,j) pairs; writes into red[0][nl2][j]
    for (int p = tid; p < 32 * 36; p += 256) {
        int nl2 = p / 36, j = p - nl2 * 36;
        float sum = 0.f;
#pragma unroll
        for (int e2 = 0; e2 < 8; e2++) sum += red[e2][nl2][j];
        red[0][nl2][j] = sum;     // only this thread reads/writes (nl2,j)
    }
    __syncthreads();

    // epilogue: 32 threads, one n each
    if (tid < 32) {
        const float* ur = uraw + (size_t)n * (WIN * 5);
        float b127 = cb[127];
        float acc = lb[0];
#pragma unroll
        for (int j = 0; j < 36; j++) {
            float g = b127 + red[0][tid][j];
#pragma unroll
            for (int k = 0; k < 5; k++) g += ur[(j + k) * 5 + k];
            g = (g >= 0.0f) ? g : 0.01f * g;
            acc += g * lw[j];
        }
        outp[n] = acc;
    }
}

// ---------------------------------------------------------------------------
extern "C" void kernel_launch(void* const* d_in, const int* in_sizes, int n_in,
                              void* d_out, int out_size, void* d_ws, size_t ws_size,
                              hipStream_t stream) {
    const float* x  = (const float*)d_in[0];   // [8000,64,64]
    const float* cw = (const float*)d_in[1];   // [128,144,5]
    const float* cb = (const float*)d_in[2];   // [128]
    const float* lw = (const float*)d_in[3];   // [1,36]
    const float* lb = (const float*)d_in[4];   // [1]
    float* outp = (float*)d_out;               // [8000,1]

    float* ws    = (float*)d_ws;
    float* xeT   = ws;                         // 8*59*8000
    float* rankT = ws + XET_SZ;                // 8*40*8000
    float* uraw  = ws + XET_SZ + RNK_SZ;       // 8000*40*5

    k0<<<dim3(32, 59), 256, 0, stream>>>(x, cw, xeT, uraw);
    k_rank<<<dim3(WIN, EE), 1024, 0, stream>>>(xeT, rankT);
    k_der_final<<<250, 256, 0, stream>>>(cw, xeT, rankT, uraw, cb, lw, lb, outp);
}